// Round 1
// baseline (1336.314 us; speedup 1.0000x reference)
//
#include <hip/hip_runtime.h>
#include <math.h>

// Problem constants (fixed by setup_inputs)
namespace {
constexpr int Bt = 4096;
constexpr int Nt = 32;       // tokens per batch
constexpr int Dm = 256;      // model dim = N_HEAD*D_K = N_HEAD*D_V
constexpr int NHEAD = 8;
constexpr float NEGV = -10000000000.0f;
constexpr int ATTN_BASE = Bt * Dm;            // normed is first in d_out
constexpr float INV_TEMP = 0.17677669529663687f;  // 1/sqrt(D_K)=1/sqrt(32)

// Type-selected projection: acc[n] = sum_d xs[n][d] * W[etype(n)][d][j]
// tm[e] = 32-bit bitmask of tokens with type e (wave-uniform -> scalar branches).
__device__ __forceinline__ void project(const float* __restrict__ W, int j,
                                        const unsigned* tm,
                                        const float (*xs)[Dm],
                                        float* acc)
{
#pragma unroll
    for (int n = 0; n < Nt; ++n) acc[n] = 0.f;
#pragma unroll
    for (int e = 0; e < 4; ++e) {
        unsigned m = tm[e];
        if (m == 0) continue;
        const float* We = W + e * (Dm * Dm) + j;
        for (int d0 = 0; d0 < Dm; d0 += 16) {
            float w[16];
#pragma unroll
            for (int dd = 0; dd < 16; ++dd) w[dd] = We[(d0 + dd) * Dm];
#pragma unroll
            for (int n = 0; n < Nt; ++n) {
                if (m & (1u << n)) {   // uniform: s_and + s_cbranch, co-issues with VALU
#pragma unroll
                    for (int c = 0; c < 4; ++c) {
                        float4 xv = *(const float4*)&xs[n][d0 + c * 4];
                        acc[n] = fmaf(xv.x, w[c * 4 + 0], acc[n]);
                        acc[n] = fmaf(xv.y, w[c * 4 + 1], acc[n]);
                        acc[n] = fmaf(xv.z, w[c * 4 + 2], acc[n]);
                        acc[n] = fmaf(xv.w, w[c * 4 + 3], acc[n]);
                    }
                }
            }
        }
    }
}
} // namespace

__global__ __launch_bounds__(256)
void mha_fused_kernel(const float* __restrict__ q, const float* __restrict__ k,
                      const float* __restrict__ v,
                      const float* __restrict__ Wq, const float* __restrict__ Wk,
                      const float* __restrict__ Wv,
                      const float* __restrict__ rel_pri,
                      const float* __restrict__ fc_w, const float* __restrict__ fc_b,
                      const float* __restrict__ gamma, const float* __restrict__ beta,
                      const int* __restrict__ seq_etype, const int* __restrict__ seq_utype,
                      const int* __restrict__ mask,
                      float* __restrict__ out)
{
    const int b = blockIdx.x;
    const int j = threadIdx.x;      // output column 0..255
    const int h = j >> 5;           // head
    const int l = j & 31;           // lane within head (== token index for softmax)

    __shared__ __align__(16) float xs[Nt][Dm];   // 32 KB staging for q/k/v of this batch
    __shared__ __align__(16) float outbuf[Dm];
    __shared__ float attn_s[NHEAD][Nt];
    __shared__ float pri_s[Nt];
    __shared__ int   msks[Nt];
    __shared__ unsigned tmask_s[4];
    __shared__ int   ut_s;
    __shared__ float redA[4], redB[4];

    // ---- metadata ----
    if (j < 4) tmask_s[j] = 0u;
    if (j == 0) ut_s = seq_utype[b];
    __syncthreads();
    if (j < Nt) {
        int e = seq_etype[b * Nt + j];
        msks[j] = mask[b * Nt + j];
        pri_s[j] = rel_pri[ut_s * 4 + e] * INV_TEMP;
        atomicOr(&tmask_s[e], 1u << j);
    }
    __syncthreads();

    unsigned tm[4];
#pragma unroll
    for (int e = 0; e < 4; ++e) tm[e] = __builtin_amdgcn_readfirstlane(tmask_s[e]);
    const int ut = __builtin_amdgcn_readfirstlane(ut_s);

    // ---- stage q, project Q ----
    {
        const float4* s4 = (const float4*)(q + (size_t)b * (Nt * Dm));
        float4* d4 = (float4*)&xs[0][0];
#pragma unroll
        for (int r = 0; r < 8; ++r) d4[r * 256 + j] = s4[r * 256 + j];
    }
    __syncthreads();
    float Qacc[Nt];
    project(Wq, j, tm, xs, Qacc);
    __syncthreads();

    // ---- stage k, project K ----
    {
        const float4* s4 = (const float4*)(k + (size_t)b * (Nt * Dm));
        float4* d4 = (float4*)&xs[0][0];
#pragma unroll
        for (int r = 0; r < 8; ++r) d4[r * 256 + j] = s4[r * 256 + j];
    }
    __syncthreads();
    float Kacc[Nt];
    project(Wk, j, tm, xs, Kacc);

    // ---- scores: sc = score for token l of head h (reduce over 32 cols of head) ----
    float sc = 0.f;
#pragma unroll
    for (int n = 0; n < Nt; ++n) {
        float p = Qacc[n] * Kacc[n];
#pragma unroll
        for (int off = 16; off >= 1; off >>= 1) p += __shfl_xor(p, off, 64);
        sc = (l == n) ? p : sc;
    }

    // ---- scale, mask, softmax over 32 tokens (lanes of 32-group) ----
    sc = sc * pri_s[l];
    if (msks[l] != 0) sc = NEGV;
    float mx = sc;
#pragma unroll
    for (int off = 16; off >= 1; off >>= 1) mx = fmaxf(mx, __shfl_xor(mx, off, 64));
    float ex = expf(sc - mx);
    float sum = ex;
#pragma unroll
    for (int off = 16; off >= 1; off >>= 1) sum += __shfl_xor(sum, off, 64);
    float at = ex / sum;
    attn_s[h][l] = at;
    // attn_flat[(h*B + b)*N + n]
    out[ATTN_BASE + h * (Bt * Nt) + b * Nt + l] = at;

    // ---- stage v, project V ----
    __syncthreads();   // everyone done reading xs(k)
    {
        const float4* s4 = (const float4*)(v + (size_t)b * (Nt * Dm));
        float4* d4 = (float4*)&xs[0][0];
#pragma unroll
        for (int r = 0; r < 8; ++r) d4[r * 256 + j] = s4[r * 256 + j];
    }
    __syncthreads();
    float Vacc[Nt];
    project(Wv, j, tm, xs, Vacc);

    // ---- attention output: o[j] = sum_n attn[h][n] * V[n][j] ----
    float o = 0.f;
#pragma unroll
    for (int n = 0; n < Nt; ++n) o = fmaf(attn_s[h][n], Vacc[n], o);
    outbuf[j] = o;
    __syncthreads();

    // ---- fc: proj[j] = fc_b[ut][j] + sum_i outbuf[i] * fc_w[ut][i][j] ----
    const float* Wf = fc_w + ut * (Dm * Dm) + j;
    float pj = fc_b[ut * Dm + j];
    for (int i0 = 0; i0 < Dm; i0 += 4) {
        float4 ov = *(const float4*)&outbuf[i0];
        pj = fmaf(ov.x, Wf[(i0 + 0) * Dm], pj);
        pj = fmaf(ov.y, Wf[(i0 + 1) * Dm], pj);
        pj = fmaf(ov.z, Wf[(i0 + 2) * Dm], pj);
        pj = fmaf(ov.w, Wf[(i0 + 3) * Dm], pj);
    }

    // ---- LayerNorm over 256 columns (block-wide reduction) ----
    float s1 = pj, s2 = pj * pj;
#pragma unroll
    for (int off = 32; off >= 1; off >>= 1) {
        s1 += __shfl_xor(s1, off, 64);
        s2 += __shfl_xor(s2, off, 64);
    }
    const int w = j >> 6;
    if ((j & 63) == 0) { redA[w] = s1; redB[w] = s2; }
    __syncthreads();
    float t1 = redA[0] + redA[1] + redA[2] + redA[3];
    float t2 = redB[0] + redB[1] + redB[2] + redB[3];
    float mu = t1 * (1.f / 256.f);
    float var = t2 * (1.f / 256.f) - mu * mu;
    float inv = rsqrtf(var + 1e-5f);
    out[b * Dm + j] = (pj - mu) * inv * gamma[j] + beta[j];
}

extern "C" void kernel_launch(void* const* d_in, const int* in_sizes, int n_in,
                              void* d_out, int out_size, void* d_ws, size_t ws_size,
                              hipStream_t stream) {
    const float* q       = (const float*)d_in[0];
    const float* k       = (const float*)d_in[1];
    const float* v       = (const float*)d_in[2];
    const float* Wq      = (const float*)d_in[3];
    const float* Wk      = (const float*)d_in[4];
    const float* Wv      = (const float*)d_in[5];
    const float* rel_pri = (const float*)d_in[6];
    const float* fc_w    = (const float*)d_in[7];
    const float* fc_b    = (const float*)d_in[8];
    const float* gamma   = (const float*)d_in[9];
    const float* beta    = (const float*)d_in[10];
    const int* seq_etype = (const int*)d_in[11];
    const int* seq_utype = (const int*)d_in[12];
    const int* mask      = (const int*)d_in[13];
    float* outp = (float*)d_out;

    mha_fused_kernel<<<Bt, 256, 0, stream>>>(q, k, v, Wq, Wk, Wv, rel_pri,
                                             fc_w, fc_b, gamma, beta,
                                             seq_etype, seq_utype, mask, outp);
}